// Round 1
// baseline (992.678 us; speedup 1.0000x reference)
//
#include <hip/hip_runtime.h>
#include <cstdint>
#include <cstddef>

// Problem constants (B=8, S=2048, EMB=768, H=4, Dh=192)
#define EMB   768
#define HEADS 4
#define HD    192
#define BATCH 8
#define SEQ   2048
#define MROWS (BATCH * SEQ)   // 16384

typedef __attribute__((ext_vector_type(8))) short bf16x8;   // 8 bf16 = 4 VGPRs (MFMA A/B frag)
typedef __attribute__((ext_vector_type(4))) float f32x4;    // MFMA C/D frag

__device__ __forceinline__ unsigned short f2bf(float f) {
    union { float f; unsigned int u; } v; v.f = f;
    unsigned int u = v.u;
    unsigned int r = u + 0x7fffu + ((u >> 16) & 1u);  // RNE
    return (unsigned short)(r >> 16);
}

__device__ __forceinline__ unsigned long long pack4bf(float4 f) {
    unsigned long long a = f2bf(f.x);
    unsigned long long b = f2bf(f.y);
    unsigned long long c = f2bf(f.z);
    unsigned long long d = f2bf(f.w);
    return a | (b << 16) | (c << 32) | (d << 48);
}

// ---------------------------------------------------------------------------
// Projection GEMM:  out[b,h,s,d] = bf16( (X[m,:] . W[j,:] + bias[j]) * scale )
// X: [16384,768] f32 row-major, W: [768,768] f32 row-major (NT gemm: both K-contig)
// Tile: BM=128, BN=128, BK=32. 256 threads = 4 waves in 2x2, each wave 64x64.
// ---------------------------------------------------------------------------
__global__ __launch_bounds__(256) void proj_kernel(
    const float* __restrict__ X,
    const float* __restrict__ W,
    const float* __restrict__ bias,
    unsigned short* __restrict__ out,   // [B,H,S,HD] bf16
    float scale)
{
    __shared__ __align__(16) unsigned short Al[128 * 40];   // 128 x 32 (+8 pad)
    __shared__ __align__(16) unsigned short Bl[128 * 40];

    const int tid  = threadIdx.x;
    const int m0   = blockIdx.x * 128;
    const int n0   = blockIdx.y * 128;
    const int w    = tid >> 6;
    const int lane = tid & 63;
    const int l15  = lane & 15;
    const int quad = lane >> 4;
    const int wm   = (w >> 1) * 64;
    const int wn   = (w & 1) * 64;

    f32x4 acc[4][4];
#pragma unroll
    for (int a = 0; a < 4; a++)
#pragma unroll
        for (int b = 0; b < 4; b++) acc[a][b] = (f32x4)0.0f;

    for (int k0 = 0; k0 < 768; k0 += 32) {
        __syncthreads();
#pragma unroll
        for (int i = 0; i < 4; i++) {
            int u   = tid + i * 256;
            int row = u >> 3;
            int c4  = (u & 7) * 4;
            float4 fa = *(const float4*)(X + (size_t)(m0 + row) * 768 + k0 + c4);
            *(unsigned long long*)&Al[row * 40 + c4] = pack4bf(fa);
            float4 fb = *(const float4*)(W + (size_t)(n0 + row) * 768 + k0 + c4);
            *(unsigned long long*)&Bl[row * 40 + c4] = pack4bf(fb);
        }
        __syncthreads();

        bf16x8 af[4], bfr[4];
#pragma unroll
        for (int mi = 0; mi < 4; mi++)
            af[mi] = *(const bf16x8*)&Al[(wm + mi * 16 + l15) * 40 + quad * 8];
#pragma unroll
        for (int ni = 0; ni < 4; ni++)
            bfr[ni] = *(const bf16x8*)&Bl[(wn + ni * 16 + l15) * 40 + quad * 8];
#pragma unroll
        for (int mi = 0; mi < 4; mi++)
#pragma unroll
            for (int ni = 0; ni < 4; ni++)
                acc[mi][ni] = __builtin_amdgcn_mfma_f32_16x16x32_bf16(
                    af[mi], bfr[ni], acc[mi][ni], 0, 0, 0);
    }

    // epilogue: D layout col=lane&15, row=quad*4+reg
    const int b = m0 >> 11;   // which batch (tiles never straddle: 2048 % 128 == 0)
#pragma unroll
    for (int mi = 0; mi < 4; mi++) {
#pragma unroll
        for (int ni = 0; ni < 4; ni++) {
            int jj = n0 + wn + ni * 16 + l15;
            int h  = jj / HD;
            int d  = jj - h * HD;
            float bj = bias[jj];
#pragma unroll
            for (int r = 0; r < 4; r++) {
                int i = m0 + wm + mi * 16 + quad * 4 + r;
                int s = i & (SEQ - 1);
                out[(size_t)((b * HEADS + h) * SEQ + s) * HD + d] =
                    f2bf((acc[mi][ni][r] + bj) * scale);
            }
        }
    }
}

// ---------------------------------------------------------------------------
// Flash attention. Q pre-scaled by 1/sqrt(HD). Layouts [B,H,S,HD] bf16.
// Block: 64 Q-rows of one (b,h). 4 waves x 16 rows. K-tiles of 64 keys.
// kv buffer holds K-tile [64][200] for QK^T, then V^T [192][72] for PV.
// ---------------------------------------------------------------------------
__global__ __launch_bounds__(256) void attn_kernel(
    const unsigned short* __restrict__ Q,
    const unsigned short* __restrict__ K,
    const unsigned short* __restrict__ V,
    unsigned short* __restrict__ O)     // [B,S,EMB] bf16
{
    __shared__ __align__(16) unsigned short kv[13824];    // max(64*200, 192*72)
    __shared__ __align__(16) unsigned short plds[4608];   // 4 waves x 16 x 72

    const int tid  = threadIdx.x;
    const int w    = tid >> 6;
    const int lane = tid & 63;
    const int l15  = lane & 15;
    const int quad = lane >> 4;
    const int qt   = blockIdx.x;          // q-tile: 0..31
    const int bh   = blockIdx.y;          // 0..31
    const int b    = bh >> 2;
    const int h    = bh & 3;
    const size_t base = (size_t)bh * SEQ * HD;

    // ---- stage Q tile (64 x 192) into kv as [64][200], pull frags to regs
#pragma unroll
    for (int i = 0; i < 6; i++) {
        int u = tid + i * 256;
        int row = u / 24, cg = u % 24;
        int4 val = *(const int4*)(Q + base + (size_t)(qt * 64 + row) * HD + cg * 8);
        *(int4*)&kv[row * 200 + cg * 8] = val;
    }
    __syncthreads();
    bf16x8 qf[6];
#pragma unroll
    for (int kk = 0; kk < 6; kk++)
        qf[kk] = *(const bf16x8*)&kv[(w * 16 + l15) * 200 + kk * 32 + quad * 8];
    __syncthreads();

    f32x4 oacc[12];
#pragma unroll
    for (int i = 0; i < 12; i++) oacc[i] = (f32x4)0.0f;
    float mi[4] = {-1e30f, -1e30f, -1e30f, -1e30f};
    float li[4] = {0.f, 0.f, 0.f, 0.f};

    for (int kt = 0; kt < SEQ / 64; kt++) {
        // stage K tile [64][200]
#pragma unroll
        for (int i = 0; i < 6; i++) {
            int u = tid + i * 256;
            int row = u / 24, cg = u % 24;
            int4 val = *(const int4*)(K + base + (size_t)(kt * 64 + row) * HD + cg * 8);
            *(int4*)&kv[row * 200 + cg * 8] = val;
        }
        __syncthreads();

        // S (16 x 64 per wave) = Q . K^T
        f32x4 sacc[4];
#pragma unroll
        for (int nj = 0; nj < 4; nj++) sacc[nj] = (f32x4)0.0f;
#pragma unroll
        for (int kk = 0; kk < 6; kk++) {
#pragma unroll
            for (int nj = 0; nj < 4; nj++) {
                bf16x8 bfr = *(const bf16x8*)&kv[(nj * 16 + l15) * 200 + kk * 32 + quad * 8];
                sacc[nj] = __builtin_amdgcn_mfma_f32_16x16x32_bf16(qf[kk], bfr, sacc[nj], 0, 0, 0);
            }
        }
        __syncthreads();   // all waves done reading K; kv gets overwritten with V^T

        // online softmax; row = quad*4 + r lives in this wave's quad group
        float p[4][4];
#pragma unroll
        for (int r = 0; r < 4; r++) {
            float mcur = fmaxf(fmaxf(sacc[0][r], sacc[1][r]), fmaxf(sacc[2][r], sacc[3][r]));
#pragma unroll
            for (int off = 1; off < 16; off <<= 1)
                mcur = fmaxf(mcur, __shfl_xor(mcur, off, 64));
            float mnew  = fmaxf(mi[r], mcur);
            float alpha = __expf(mi[r] - mnew);
            float lsum  = 0.f;
#pragma unroll
            for (int nj = 0; nj < 4; nj++) {
                p[nj][r] = __expf(sacc[nj][r] - mnew);
                lsum += p[nj][r];
            }
#pragma unroll
            for (int off = 1; off < 16; off <<= 1)
                lsum += __shfl_xor(lsum, off, 64);
            li[r] = li[r] * alpha + lsum;
            mi[r] = mnew;
#pragma unroll
            for (int nf = 0; nf < 12; nf++) oacc[nf][r] *= alpha;
        }

        // P -> LDS (C-layout -> row-major [16][72] per wave, wave-private)
#pragma unroll
        for (int nj = 0; nj < 4; nj++)
#pragma unroll
            for (int r = 0; r < 4; r++)
                plds[w * 1152 + (quad * 4 + r) * 72 + nj * 16 + l15] = f2bf(p[nj][r]);

        // stage V^T into kv [192][72]
#pragma unroll
        for (int i = 0; i < 6; i++) {
            int u = tid + i * 256;
            int kr = u / 24, cg = u % 24;
            union { int4 v; unsigned short s[8]; } tmp;
            tmp.v = *(const int4*)(V + base + (size_t)(kt * 64 + kr) * HD + cg * 8);
#pragma unroll
            for (int e = 0; e < 8; e++)
                kv[(cg * 8 + e) * 72 + kr] = tmp.s[e];
        }
        __syncthreads();

        // O (16 x 192 per wave) += P(16x64) . V(64x192)
#pragma unroll
        for (int kk = 0; kk < 2; kk++) {
            bf16x8 afr = *(const bf16x8*)&plds[w * 1152 + l15 * 72 + kk * 32 + quad * 8];
#pragma unroll
            for (int nf = 0; nf < 12; nf++) {
                bf16x8 bfr = *(const bf16x8*)&kv[(nf * 16 + l15) * 72 + kk * 32 + quad * 8];
                oacc[nf] = __builtin_amdgcn_mfma_f32_16x16x32_bf16(afr, bfr, oacc[nf], 0, 0, 0);
            }
        }
        __syncthreads();   // V^T reads done before next K staging
    }

    // epilogue: O[b, s, h*HD + col] = oacc / l
    float inv[4];
#pragma unroll
    for (int r = 0; r < 4; r++) inv[r] = 1.0f / li[r];
#pragma unroll
    for (int nf = 0; nf < 12; nf++) {
        int col = h * HD + nf * 16 + l15;
#pragma unroll
        for (int r = 0; r < 4; r++) {
            int s = qt * 64 + w * 16 + quad * 4 + r;
            O[(size_t)(b * SEQ + s) * EMB + col] = f2bf(oacc[nf][r] * inv[r]);
        }
    }
}

// ---------------------------------------------------------------------------
// Output projection: out[m,j] = A[m,:] . Wo[j,:] + bo[j]   (A bf16, Wo f32->bf16)
// ---------------------------------------------------------------------------
__global__ __launch_bounds__(256) void oproj_kernel(
    const unsigned short* __restrict__ A,   // [16384,768] bf16
    const float* __restrict__ W,            // [768,768] f32
    const float* __restrict__ bias,
    float* __restrict__ out)                // [16384,768] f32
{
    __shared__ __align__(16) unsigned short Al[128 * 40];
    __shared__ __align__(16) unsigned short Bl[128 * 40];

    const int tid  = threadIdx.x;
    const int m0   = blockIdx.x * 128;
    const int n0   = blockIdx.y * 128;
    const int w    = tid >> 6;
    const int lane = tid & 63;
    const int l15  = lane & 15;
    const int quad = lane >> 4;
    const int wm   = (w >> 1) * 64;
    const int wn   = (w & 1) * 64;

    f32x4 acc[4][4];
#pragma unroll
    for (int a = 0; a < 4; a++)
#pragma unroll
        for (int b = 0; b < 4; b++) acc[a][b] = (f32x4)0.0f;

    for (int k0 = 0; k0 < 768; k0 += 32) {
        __syncthreads();
        // A is already bf16: 16B vector loads
#pragma unroll
        for (int i = 0; i < 2; i++) {
            int u   = tid + i * 256;
            int row = u >> 2;
            int cg  = u & 3;
            *(int4*)&Al[row * 40 + cg * 8] =
                *(const int4*)(A + (size_t)(m0 + row) * 768 + k0 + cg * 8);
        }
        // W is f32: convert inline
#pragma unroll
        for (int i = 0; i < 4; i++) {
            int u   = tid + i * 256;
            int row = u >> 3;
            int c4  = (u & 7) * 4;
            float4 fb = *(const float4*)(W + (size_t)(n0 + row) * 768 + k0 + c4);
            *(unsigned long long*)&Bl[row * 40 + c4] = pack4bf(fb);
        }
        __syncthreads();

        bf16x8 af[4], bfr[4];
#pragma unroll
        for (int mi = 0; mi < 4; mi++)
            af[mi] = *(const bf16x8*)&Al[(wm + mi * 16 + l15) * 40 + quad * 8];
#pragma unroll
        for (int ni = 0; ni < 4; ni++)
            bfr[ni] = *(const bf16x8*)&Bl[(wn + ni * 16 + l15) * 40 + quad * 8];
#pragma unroll
        for (int mi = 0; mi < 4; mi++)
#pragma unroll
            for (int ni = 0; ni < 4; ni++)
                acc[mi][ni] = __builtin_amdgcn_mfma_f32_16x16x32_bf16(
                    af[mi], bfr[ni], acc[mi][ni], 0, 0, 0);
    }

#pragma unroll
    for (int mi = 0; mi < 4; mi++) {
#pragma unroll
        for (int ni = 0; ni < 4; ni++) {
            int jj = n0 + wn + ni * 16 + l15;
            float bj = bias[jj];
#pragma unroll
            for (int r = 0; r < 4; r++) {
                int i = m0 + wm + mi * 16 + quad * 4 + r;
                out[(size_t)i * 768 + jj] = acc[mi][ni][r] + bj;
            }
        }
    }
}

// ---------------------------------------------------------------------------
extern "C" void kernel_launch(void* const* d_in, const int* in_sizes, int n_in,
                              void* d_out, int out_size, void* d_ws, size_t ws_size,
                              hipStream_t stream)
{
    const float* q  = (const float*)d_in[0];
    const float* k  = (const float*)d_in[1];
    const float* v  = (const float*)d_in[2];
    const float* Wq = (const float*)d_in[3];
    const float* bq = (const float*)d_in[4];
    const float* Wk = (const float*)d_in[5];
    const float* bk = (const float*)d_in[6];
    const float* Wv = (const float*)d_in[7];
    const float* bv = (const float*)d_in[8];
    const float* Wo = (const float*)d_in[9];
    const float* bo = (const float*)d_in[10];
    float* out = (float*)d_out;

    // workspace: Qb, Kb, Vb [B,H,S,HD] bf16 + Ob [B,S,EMB] bf16 = 100.7 MB
    unsigned short* Qb = (unsigned short*)d_ws;
    unsigned short* Kb = Qb + (size_t)MROWS * EMB;
    unsigned short* Vb = Kb + (size_t)MROWS * EMB;
    unsigned short* Ob = Vb + (size_t)MROWS * EMB;

    const float scl = 0.07216878364870323f;   // 1/sqrt(192)

    dim3 pg(MROWS / 128, EMB / 128);   // (128, 6)
    dim3 pb(256);
    proj_kernel<<<pg, pb, 0, stream>>>(q, Wq, bq, Qb, scl);
    proj_kernel<<<pg, pb, 0, stream>>>(k, Wk, bk, Kb, 1.0f);
    proj_kernel<<<pg, pb, 0, stream>>>(v, Wv, bv, Vb, 1.0f);

    dim3 ag(SEQ / 64, BATCH * HEADS);  // (32, 32)
    attn_kernel<<<ag, pb, 0, stream>>>(Qb, Kb, Vb, Ob);

    oproj_kernel<<<pg, pb, 0, stream>>>(Ob, Wo, bo, out);
}

// Round 2
// 601.196 us; speedup vs baseline: 1.6512x; 1.6512x over previous
//
#include <hip/hip_runtime.h>
#include <cstdint>
#include <cstddef>

// Problem constants (B=8, S=2048, EMB=768, H=4, Dh=192)
#define EMB   768
#define HEADS 4
#define HD    192
#define BATCH 8
#define SEQ   2048
#define MROWS (BATCH * SEQ)   // 16384

typedef __attribute__((ext_vector_type(8))) short bf16x8;   // 8 bf16 = 4 VGPRs (MFMA A/B frag)
typedef __attribute__((ext_vector_type(4))) float f32x4;    // MFMA C/D frag

__device__ __forceinline__ unsigned short f2bf(float f) {
    union { float f; unsigned int u; } v; v.f = f;
    unsigned int u = v.u;
    unsigned int r = u + 0x7fffu + ((u >> 16) & 1u);  // RNE
    return (unsigned short)(r >> 16);
}

__device__ __forceinline__ unsigned long long pack4bf(float4 f) {
    unsigned long long a = f2bf(f.x);
    unsigned long long b = f2bf(f.y);
    unsigned long long c = f2bf(f.z);
    unsigned long long d = f2bf(f.w);
    return a | (b << 16) | (c << 32) | (d << 48);
}

// ---------------------------------------------------------------------------
// Projection GEMM:  out[b,h,s,d] = bf16( (X[m,:] . W[j,:] + bias[j]) * scale )
// X: [16384,768] f32 row-major, W: [768,768] f32 row-major (NT gemm: both K-contig)
// Tile: BM=128, BN=128, BK=32. 256 threads = 4 waves in 2x2, each wave 64x64.
// ---------------------------------------------------------------------------
__global__ __launch_bounds__(256) void proj_kernel(
    const float* __restrict__ X,
    const float* __restrict__ W,
    const float* __restrict__ bias,
    unsigned short* __restrict__ out,   // [B,H,S,HD] bf16
    float scale)
{
    __shared__ __align__(16) unsigned short Al[128 * 40];   // 128 x 32 (+8 pad)
    __shared__ __align__(16) unsigned short Bl[128 * 40];

    const int tid  = threadIdx.x;
    const int m0   = blockIdx.x * 128;
    const int n0   = blockIdx.y * 128;
    const int w    = tid >> 6;
    const int lane = tid & 63;
    const int l15  = lane & 15;
    const int quad = lane >> 4;
    const int wm   = (w >> 1) * 64;
    const int wn   = (w & 1) * 64;

    f32x4 acc[4][4];
#pragma unroll
    for (int a = 0; a < 4; a++)
#pragma unroll
        for (int b = 0; b < 4; b++) acc[a][b] = (f32x4)0.0f;

    for (int k0 = 0; k0 < 768; k0 += 32) {
        __syncthreads();
#pragma unroll
        for (int i = 0; i < 4; i++) {
            int u   = tid + i * 256;
            int row = u >> 3;
            int c4  = (u & 7) * 4;
            float4 fa = *(const float4*)(X + (size_t)(m0 + row) * 768 + k0 + c4);
            *(unsigned long long*)&Al[row * 40 + c4] = pack4bf(fa);
            float4 fb = *(const float4*)(W + (size_t)(n0 + row) * 768 + k0 + c4);
            *(unsigned long long*)&Bl[row * 40 + c4] = pack4bf(fb);
        }
        __syncthreads();

        bf16x8 af[4], bfr[4];
#pragma unroll
        for (int mi = 0; mi < 4; mi++)
            af[mi] = *(const bf16x8*)&Al[(wm + mi * 16 + l15) * 40 + quad * 8];
#pragma unroll
        for (int ni = 0; ni < 4; ni++)
            bfr[ni] = *(const bf16x8*)&Bl[(wn + ni * 16 + l15) * 40 + quad * 8];
#pragma unroll
        for (int mi = 0; mi < 4; mi++)
#pragma unroll
            for (int ni = 0; ni < 4; ni++)
                acc[mi][ni] = __builtin_amdgcn_mfma_f32_16x16x32_bf16(
                    af[mi], bfr[ni], acc[mi][ni], 0, 0, 0);
    }

    // epilogue: D layout col=lane&15, row=quad*4+reg
    const int b = m0 >> 11;   // which batch (tiles never straddle: 2048 % 128 == 0)
#pragma unroll
    for (int mi = 0; mi < 4; mi++) {
#pragma unroll
        for (int ni = 0; ni < 4; ni++) {
            int jj = n0 + wn + ni * 16 + l15;
            int h  = jj / HD;
            int d  = jj - h * HD;
            float bj = bias[jj];
#pragma unroll
            for (int r = 0; r < 4; r++) {
                int i = m0 + wm + mi * 16 + quad * 4 + r;
                int s = i & (SEQ - 1);
                out[(size_t)((b * HEADS + h) * SEQ + s) * HD + d] =
                    f2bf((acc[mi][ni][r] + bj) * scale);
            }
        }
    }
}

// ---------------------------------------------------------------------------
// Flash attention. Q pre-scaled by 1/sqrt(HD). Layouts [B,H,S,HD] bf16.
// Block: 64 Q-rows of one (b,h). 4 waves x 16 rows. K-tiles of 64 keys.
// kv buffer holds K-tile [64][200] for QK^T, then V^T [192][72] for PV.
// Bank notes (dword strides mod 32): K rows 100 dw (=4) -> uniform;
// V^T rows 36 dw (=4) -> uniform reads; P rows 34 dw (=2) -> uniform reads,
// quad-stride 8 on writes -> conflict-free. V^T writes: lane==key-row so
// each write instr spans 32 consecutive dwords -> conflict-free.
// ---------------------------------------------------------------------------
__global__ __launch_bounds__(256) void attn_kernel(
    const unsigned short* __restrict__ Q,
    const unsigned short* __restrict__ K,
    const unsigned short* __restrict__ V,
    unsigned short* __restrict__ O)     // [B,S,EMB] bf16
{
    __shared__ __align__(16) unsigned short kv[13824];    // max(64*200, 192*72)
    __shared__ __align__(16) unsigned short plds[4352];   // 4 waves x 16 x 68

    const int tid  = threadIdx.x;
    const int w    = tid >> 6;
    const int lane = tid & 63;
    const int l15  = lane & 15;
    const int quad = lane >> 4;
    const int qt   = blockIdx.x;          // q-tile: 0..31
    const int bh   = blockIdx.y;          // 0..31
    const int b    = bh >> 2;
    const int h    = bh & 3;
    const size_t base = (size_t)bh * SEQ * HD;

    // ---- stage Q tile (64 x 192) into kv as [64][200], pull frags to regs
#pragma unroll
    for (int i = 0; i < 6; i++) {
        int u = tid + i * 256;
        int row = u / 24, cg = u % 24;
        int4 val = *(const int4*)(Q + base + (size_t)(qt * 64 + row) * HD + cg * 8);
        *(int4*)&kv[row * 200 + cg * 8] = val;
    }
    __syncthreads();
    bf16x8 qf[6];
#pragma unroll
    for (int kk = 0; kk < 6; kk++)
        qf[kk] = *(const bf16x8*)&kv[(w * 16 + l15) * 200 + kk * 32 + quad * 8];
    __syncthreads();

    f32x4 oacc[12];
#pragma unroll
    for (int i = 0; i < 12; i++) oacc[i] = (f32x4)0.0f;
    float mi[4] = {-1e30f, -1e30f, -1e30f, -1e30f};
    float li[4] = {0.f, 0.f, 0.f, 0.f};

    for (int kt = 0; kt < SEQ / 64; kt++) {
        // stage K tile [64][200]
#pragma unroll
        for (int i = 0; i < 6; i++) {
            int u = tid + i * 256;
            int row = u / 24, cg = u % 24;
            int4 val = *(const int4*)(K + base + (size_t)(kt * 64 + row) * HD + cg * 8);
            *(int4*)&kv[row * 200 + cg * 8] = val;
        }
        __syncthreads();

        // S (16 x 64 per wave) = Q . K^T
        f32x4 sacc[4];
#pragma unroll
        for (int nj = 0; nj < 4; nj++) sacc[nj] = (f32x4)0.0f;
#pragma unroll
        for (int kk = 0; kk < 6; kk++) {
#pragma unroll
            for (int nj = 0; nj < 4; nj++) {
                bf16x8 bfr = *(const bf16x8*)&kv[(nj * 16 + l15) * 200 + kk * 32 + quad * 8];
                sacc[nj] = __builtin_amdgcn_mfma_f32_16x16x32_bf16(qf[kk], bfr, sacc[nj], 0, 0, 0);
            }
        }
        __syncthreads();   // all waves done reading K; kv gets overwritten with V^T

        // online softmax; row = quad*4 + r lives in this wave's quad group
        float p[4][4];
#pragma unroll
        for (int r = 0; r < 4; r++) {
            float mcur = fmaxf(fmaxf(sacc[0][r], sacc[1][r]), fmaxf(sacc[2][r], sacc[3][r]));
#pragma unroll
            for (int off = 1; off < 16; off <<= 1)
                mcur = fmaxf(mcur, __shfl_xor(mcur, off, 64));
            float mnew  = fmaxf(mi[r], mcur);
            float alpha = __expf(mi[r] - mnew);
            float lsum  = 0.f;
#pragma unroll
            for (int nj = 0; nj < 4; nj++) {
                p[nj][r] = __expf(sacc[nj][r] - mnew);
                lsum += p[nj][r];
            }
#pragma unroll
            for (int off = 1; off < 16; off <<= 1)
                lsum += __shfl_xor(lsum, off, 64);
            li[r] = li[r] * alpha + lsum;
            mi[r] = mnew;
#pragma unroll
            for (int nf = 0; nf < 12; nf++) oacc[nf][r] *= alpha;
        }

        // P -> LDS (C-layout -> row-major [16][68] per wave, wave-private)
#pragma unroll
        for (int nj = 0; nj < 4; nj++)
#pragma unroll
            for (int r = 0; r < 4; r++)
                plds[w * 1088 + (quad * 4 + r) * 68 + nj * 16 + l15] = f2bf(p[nj][r]);

        // stage V^T into kv [192][72]: lane = key-row, wave covers cg = w,w+4,...
#pragma unroll
        for (int i = 0; i < 6; i++) {
            int cg = i * 4 + w;
            union { int4 v; unsigned short s[8]; } tmp;
            tmp.v = *(const int4*)(V + base + (size_t)(kt * 64 + lane) * HD + cg * 8);
#pragma unroll
            for (int e = 0; e < 8; e++)
                kv[(cg * 8 + e) * 72 + lane] = tmp.s[e];
        }
        __syncthreads();

        // O (16 x 192 per wave) += P(16x64) . V(64x192)
#pragma unroll
        for (int kk = 0; kk < 2; kk++) {
            bf16x8 afr = *(const bf16x8*)&plds[w * 1088 + l15 * 68 + kk * 32 + quad * 8];
#pragma unroll
            for (int nf = 0; nf < 12; nf++) {
                bf16x8 bfr = *(const bf16x8*)&kv[(nf * 16 + l15) * 72 + kk * 32 + quad * 8];
                oacc[nf] = __builtin_amdgcn_mfma_f32_16x16x32_bf16(afr, bfr, oacc[nf], 0, 0, 0);
            }
        }
        __syncthreads();   // V^T reads done before next K staging
    }

    // epilogue: O[b, s, h*HD + col] = oacc / l
    float inv[4];
#pragma unroll
    for (int r = 0; r < 4; r++) inv[r] = 1.0f / li[r];
#pragma unroll
    for (int nf = 0; nf < 12; nf++) {
        int col = h * HD + nf * 16 + l15;
#pragma unroll
        for (int r = 0; r < 4; r++) {
            int s = qt * 64 + w * 16 + quad * 4 + r;
            O[(size_t)(b * SEQ + s) * EMB + col] = f2bf(oacc[nf][r] * inv[r]);
        }
    }
}

// ---------------------------------------------------------------------------
// Output projection: out[m,j] = A[m,:] . Wo[j,:] + bo[j]   (A bf16, Wo f32->bf16)
// ---------------------------------------------------------------------------
__global__ __launch_bounds__(256) void oproj_kernel(
    const unsigned short* __restrict__ A,   // [16384,768] bf16
    const float* __restrict__ W,            // [768,768] f32
    const float* __restrict__ bias,
    float* __restrict__ out)                // [16384,768] f32
{
    __shared__ __align__(16) unsigned short Al[128 * 40];
    __shared__ __align__(16) unsigned short Bl[128 * 40];

    const int tid  = threadIdx.x;
    const int m0   = blockIdx.x * 128;
    const int n0   = blockIdx.y * 128;
    const int w    = tid >> 6;
    const int lane = tid & 63;
    const int l15  = lane & 15;
    const int quad = lane >> 4;
    const int wm   = (w >> 1) * 64;
    const int wn   = (w & 1) * 64;

    f32x4 acc[4][4];
#pragma unroll
    for (int a = 0; a < 4; a++)
#pragma unroll
        for (int b = 0; b < 4; b++) acc[a][b] = (f32x4)0.0f;

    for (int k0 = 0; k0 < 768; k0 += 32) {
        __syncthreads();
        // A is already bf16: 16B vector loads
#pragma unroll
        for (int i = 0; i < 2; i++) {
            int u   = tid + i * 256;
            int row = u >> 2;
            int cg  = u & 3;
            *(int4*)&Al[row * 40 + cg * 8] =
                *(const int4*)(A + (size_t)(m0 + row) * 768 + k0 + cg * 8);
        }
        // W is f32: convert inline
#pragma unroll
        for (int i = 0; i < 4; i++) {
            int u   = tid + i * 256;
            int row = u >> 3;
            int c4  = (u & 7) * 4;
            float4 fb = *(const float4*)(W + (size_t)(n0 + row) * 768 + k0 + c4);
            *(unsigned long long*)&Bl[row * 40 + c4] = pack4bf(fb);
        }
        __syncthreads();

        bf16x8 af[4], bfr[4];
#pragma unroll
        for (int mi = 0; mi < 4; mi++)
            af[mi] = *(const bf16x8*)&Al[(wm + mi * 16 + l15) * 40 + quad * 8];
#pragma unroll
        for (int ni = 0; ni < 4; ni++)
            bfr[ni] = *(const bf16x8*)&Bl[(wn + ni * 16 + l15) * 40 + quad * 8];
#pragma unroll
        for (int mi = 0; mi < 4; mi++)
#pragma unroll
            for (int ni = 0; ni < 4; ni++)
                acc[mi][ni] = __builtin_amdgcn_mfma_f32_16x16x32_bf16(
                    af[mi], bfr[ni], acc[mi][ni], 0, 0, 0);
    }

#pragma unroll
    for (int mi = 0; mi < 4; mi++) {
#pragma unroll
        for (int ni = 0; ni < 4; ni++) {
            int jj = n0 + wn + ni * 16 + l15;
            float bj = bias[jj];
#pragma unroll
            for (int r = 0; r < 4; r++) {
                int i = m0 + wm + mi * 16 + quad * 4 + r;
                out[(size_t)i * 768 + jj] = acc[mi][ni][r] + bj;
            }
        }
    }
}

// ---------------------------------------------------------------------------
extern "C" void kernel_launch(void* const* d_in, const int* in_sizes, int n_in,
                              void* d_out, int out_size, void* d_ws, size_t ws_size,
                              hipStream_t stream)
{
    const float* q  = (const float*)d_in[0];
    const float* k  = (const float*)d_in[1];
    const float* v  = (const float*)d_in[2];
    const float* Wq = (const float*)d_in[3];
    const float* bq = (const float*)d_in[4];
    const float* Wk = (const float*)d_in[5];
    const float* bk = (const float*)d_in[6];
    const float* Wv = (const float*)d_in[7];
    const float* bv = (const float*)d_in[8];
    const float* Wo = (const float*)d_in[9];
    const float* bo = (const float*)d_in[10];
    float* out = (float*)d_out;

    // workspace: Qb, Kb, Vb [B,H,S,HD] bf16 + Ob [B,S,EMB] bf16 = 100.7 MB
    unsigned short* Qb = (unsigned short*)d_ws;
    unsigned short* Kb = Qb + (size_t)MROWS * EMB;
    unsigned short* Vb = Kb + (size_t)MROWS * EMB;
    unsigned short* Ob = Vb + (size_t)MROWS * EMB;

    const float scl = 0.07216878364870323f;   // 1/sqrt(192)

    dim3 pg(MROWS / 128, EMB / 128);   // (128, 6)
    dim3 pb(256);
    proj_kernel<<<pg, pb, 0, stream>>>(q, Wq, bq, Qb, scl);
    proj_kernel<<<pg, pb, 0, stream>>>(k, Wk, bk, Kb, 1.0f);
    proj_kernel<<<pg, pb, 0, stream>>>(v, Wv, bv, Vb, 1.0f);

    dim3 ag(SEQ / 64, BATCH * HEADS);  // (32, 32)
    attn_kernel<<<ag, pb, 0, stream>>>(Qb, Kb, Vb, Ob);

    oproj_kernel<<<pg, pb, 0, stream>>>(Ob, Wo, bo, out);
}